// Round 9
// baseline (861.672 us; speedup 1.0000x reference)
//
#include <hip/hip_runtime.h>

#define HH 512
#define WW 512
#define HWC (HH * WW)          // 262144 = 2^18
#define NV 50000
#define NB 4
#define NR (NB * NV)           // 200000 rows per branch
#define NQ (2 * NR)            // 400000 total queries

typedef unsigned int uint32;
typedef unsigned short ushort16;

static __device__ __forceinline__ float4 ld4(const float* p) {
    return *reinterpret_cast<const float4*>(p);
}
// round-to-nearest-even f32 -> bf16 (as low 16 bits)
static __device__ __forceinline__ uint32 bf16rne(float x) {
    uint32 u = __float_as_uint(x);
    return (u + 0x7FFFu + ((u >> 16) & 1u)) >> 16;
}
static __device__ __forceinline__ float bf16f(uint32 h) {
    return __uint_as_float(h << 16);
}

// Sum across each 16-lane row via DPP (VALU pipe, no LDS).
static __device__ __forceinline__ float red16(float x) {
    float t;
    t = __int_as_float(__builtin_amdgcn_update_dpp(0, __float_as_int(x), 0xB1, 0xF, 0xF, true));  // quad_perm(1,0,3,2)
    x += t;
    t = __int_as_float(__builtin_amdgcn_update_dpp(0, __float_as_int(x), 0x4E, 0xF, 0xF, true));  // quad_perm(2,3,0,1)
    x += t;
    t = __int_as_float(__builtin_amdgcn_update_dpp(0, __float_as_int(x), 0x141, 0xF, 0xF, true)); // row_half_mirror
    x += t;
    t = __int_as_float(__builtin_amdgcn_update_dpp(0, __float_as_int(x), 0x140, 0xF, 0xF, true)); // row_mirror
    x += t;
    return x;
}

// ---------------------------------------------------------------------------
// K0: fast -1 fill of the grids buffer.
// ---------------------------------------------------------------------------
__global__ void k_fill(int4* __restrict__ p) {
    const int total = 2 * NB * HWC / 4;
    const int stride = gridDim.x * blockDim.x;
    const int4 v = make_int4(-1, -1, -1, -1);
    for (int i = blockIdx.x * blockDim.x + threadIdx.x; i < total; i += stride)
        p[i] = v;
}

// ---------------------------------------------------------------------------
// K1: scatter voxel indices into dense coord->index grids
// grids layout: [set(0=li,1=ra)][b][HWC], pre-filled with -1
// ---------------------------------------------------------------------------
__global__ void k_grid(const int* __restrict__ li_coors, const int* __restrict__ ra_coors,
                       int* __restrict__ grids) {
    int t = blockIdx.x * blockDim.x + threadIdx.x;
    if (t >= NQ) return;
    int set = t / NR;
    int r2 = t - set * NR;
    int b = r2 / NV;
    int n = r2 - b * NV;
    const int* co = (set == 0 ? li_coors : ra_coors) + (size_t)(b * NV + n) * 2;
    grids[(set * NB + b) * HWC + co[0] * WW + co[1]] = n;
}

// ---------------------------------------------------------------------------
// K2: combined projection, ONE-SHOT wave structure (no grid-stride loop:
// round-8 profile showed the serial per-wave loop was latency-bound at
// 159us for 102MB). blockIdx.y = f (feats tensor). One wave = one row pair.
// Outputs bf16: Qbuf[f] (ushort) and packed KV[f^1] (uint: K low16, V high16).
// ---------------------------------------------------------------------------
__launch_bounds__(256)
__global__ void k_proj_all(const float* __restrict__ li_feats, const float* __restrict__ ra_feats,
                           const float* __restrict__ w_qkv1, const float* __restrict__ b_qkv1,
                           const float* __restrict__ w_qkv2, const float* __restrict__ b_qkv2,
                           ushort16* __restrict__ Qbuf, uint32* __restrict__ KV) {
    const int f = blockIdx.y;
    const float* feats = f ? ra_feats : li_feats;
    const float* wq_g  = f ? w_qkv2 : w_qkv1;   // queries of branch f
    const float* bq_g  = f ? b_qkv2 : b_qkv1;
    const float* wkv_g = f ? w_qkv1 : w_qkv2;   // keys/values consumed by branch f^1
    const float* bkv_g = f ? b_qkv1 : b_qkv2;

    __shared__ float xs[4][64];
    const int wave = threadIdx.x >> 6;
    const int l    = threadIdx.x & 63;
    const int h    = l >> 5;         // which row of the pair
    const int j    = l & 31;         // output column

    const int r0 = (blockIdx.x * 4 + wave) * 2;   // exact grid: always < NR

    // issue the feats row-pair load first; weight loads overlap its latency
    xs[wave][l] = feats[(size_t)r0 * 32 + l];

    float4 wq[8], wk[8], wv[8];
#pragma unroll
    for (int i = 0; i < 8; ++i) {
        wq[i] = ld4(wq_g  + j * 32 + i * 4);
        wk[i] = ld4(wkv_g + (32 + j) * 32 + i * 4);
        wv[i] = ld4(wkv_g + (64 + j) * 32 + i * 4);
    }
    const float bq = bq_g[j], bk = bkv_g[32 + j], bv = bkv_g[64 + j];

    const float* xp = &xs[wave][h * 32];
    float aq = bq, ak = bk, av = bv;
#pragma unroll
    for (int i = 0; i < 8; ++i) {
        float4 x = *reinterpret_cast<const float4*>(xp + i * 4);  // broadcast
        aq += x.x * wq[i].x + x.y * wq[i].y + x.z * wq[i].z + x.w * wq[i].w;
        ak += x.x * wk[i].x + x.y * wk[i].y + x.z * wk[i].z + x.w * wk[i].w;
        av += x.x * wv[i].x + x.y * wv[i].y + x.z * wv[i].z + x.w * wv[i].w;
    }
    const int row = r0 + h;
    ushort16* Qb = Qbuf + (size_t)f * NR * 32;
    uint32*  KVb = KV + (size_t)(f ^ 1) * NR * 32;
    Qb[(size_t)row * 32 + j] = (ushort16)bf16rne(aq);
    KVb[(size_t)row * 32 + j] = bf16rne(ak) | (bf16rne(av) << 16);
}

// ---------------------------------------------------------------------------
// K3a: neighbor resolve. 1 thread per query; 9 independent grid loads.
// Writes [q][12]: idx0..8 (clamped), mask, pad, pad.
// ---------------------------------------------------------------------------
__global__ void k_nbr(const int* __restrict__ li_coors, const int* __restrict__ ra_coors,
                      const int* __restrict__ grids, int* __restrict__ nbr) {
    int q = blockIdx.x * 256 + threadIdx.x;
    if (q >= NQ) return;
    int br  = (q >= NR) ? 1 : 0;
    int rem = q - br * NR;
    int b   = rem / NV;
    const int* qc = br ? ra_coors : li_coors;
    const int* kvgrid = grids + ((br ^ 1) * NB + b) * HWC;
    const int2 rc = *reinterpret_cast<const int2*>(qc + (size_t)rem * 2);

    const int drs[9] = {0, -1, 1, 0, -1, 1, 0, -1, 1};
    const int dcs[9] = {0, 0, 0, 1, 1, 1, -1, -1, -1};
    int v[9];
    int mask = 0;
#pragma unroll
    for (int k = 0; k < 9; ++k) {
        int rr = rc.x + drs[k], cc = rc.y + dcs[k];
        bool valid = ((unsigned)rr < HH) & ((unsigned)cc < WW);
        int raw = kvgrid[valid ? rr * WW + cc : 0];
        int id = valid ? raw : -1;
        mask |= (int)(id >= 0) << k;
        v[k] = id > 0 ? id : 0;
    }
    int4* np = reinterpret_cast<int4*>(nbr + (size_t)q * 12);
    np[0] = make_int4(v[0], v[1], v[2], v[3]);
    np[1] = make_int4(v[4], v[5], v[6], v[7]);
    np[2] = make_int4(v[8], mask, 0, 0);
}

// ---------------------------------------------------------------------------
// K3b: slim attention core. 32 lanes per query, 4 queries per lane-group
// (36 outstanding u32 gathers/lane). bf16 Q/K/V; writes bf16 o.
// ---------------------------------------------------------------------------
__launch_bounds__(256)
__global__ void k_attn(const int* __restrict__ nbr, const ushort16* __restrict__ Qbuf,
                       const uint32* __restrict__ KV,
                       const float* __restrict__ b_qkv1, const float* __restrict__ b_qkv2,
                       ushort16* __restrict__ obuf) {
    const int g = threadIdx.x >> 5;
    const int j = threadIdx.x & 31;
    const int q0 = (blockIdx.x * 8 + g) * 4;   // 4 queries, never straddle b/br
    const int br  = (q0 >= NR) ? 1 : 0;
    const int rem = q0 - br * NR;
    const int bb  = rem / NV;
    const uint32* KVbb = KV + ((size_t)br * NR + (size_t)bb * NV) * 32;
    const float* bqkv = br ? b_qkv2 : b_qkv1;

    int4 a0[4], a1[4], a2[4];
#pragma unroll
    for (int u = 0; u < 4; ++u) {
        const int4* np = reinterpret_cast<const int4*>(nbr + (size_t)(q0 + u) * 12);
        a0[u] = np[0]; a1[u] = np[1]; a2[u] = np[2];
    }
    float Qf[4];
#pragma unroll
    for (int u = 0; u < 4; ++u) Qf[u] = bf16f(Qbuf[(size_t)(q0 + u) * 32 + j]);
    const float bk = bqkv[32 + j], bv = bqkv[64 + j];

    // batched gathers: 36 independent u32 loads
    uint32 kvw[4][9];
#pragma unroll
    for (int u = 0; u < 4; ++u) {
        int id[9] = {a0[u].x, a0[u].y, a0[u].z, a0[u].w,
                     a1[u].x, a1[u].y, a1[u].z, a1[u].w, a2[u].x};
#pragma unroll
        for (int k = 0; k < 9; ++k)
            kvw[u][k] = KVbb[(size_t)id[k] * 32 + j];
    }

#pragma unroll
    for (int u = 0; u < 4; ++u) {
        const int mask = a2[u].y;
        float sc[9];
#pragma unroll
        for (int k = 0; k < 9; ++k) {
            float kk = ((mask >> k) & 1) ? __uint_as_float(kvw[u][k] << 16) : bk;
            sc[k] = red16(Qf[u] * kk) * 0.25f;  // 1/sqrt(HD=16)
        }
        float m = sc[0];
#pragma unroll
        for (int k = 1; k < 9; ++k) m = fmaxf(m, sc[k]);
        float sum = 0.f, o = 0.f;
#pragma unroll
        for (int k = 0; k < 9; ++k) {
            float e = __expf(sc[k] - m);
            float vv = ((mask >> k) & 1) ? __uint_as_float(kvw[u][k] & 0xFFFF0000u) : bv;
            sum += e;
            o += e * vv;
        }
        obuf[(size_t)(q0 + u) * 32 + j] = (ushort16)bf16rne(o / sum);
    }
}

// ---------------------------------------------------------------------------
// K3c: out-projection + residual, ONE-SHOT wave structure (same fix as K2).
// blockIdx.y = branch. One wave = one row pair. Reads bf16 o rows via LDS,
// writes fp32 res rows.
// ---------------------------------------------------------------------------
__launch_bounds__(256)
__global__ void k_outproj(const float* __restrict__ li_feats, const float* __restrict__ ra_feats,
                          const float* __restrict__ w_out1, const float* __restrict__ b_out1,
                          const float* __restrict__ w_out2, const float* __restrict__ b_out2,
                          const ushort16* __restrict__ obuf, float* __restrict__ res) {
    const int br = blockIdx.y;
    const float* wout = br ? w_out2 : w_out1;
    const float* qf   = br ? ra_feats : li_feats;

    __shared__ float xs[4][64];
    const int wave = threadIdx.x >> 6;
    const int l    = threadIdx.x & 63;
    const int h    = l >> 5;
    const int j    = l & 31;

    const int r0 = (blockIdx.x * 4 + wave) * 2;   // exact grid: always < NR

    const ushort16* ob = obuf + (size_t)br * NR * 32;
    xs[wave][l] = bf16f(ob[(size_t)r0 * 32 + l]);  // 2 o-rows, coalesced 128B

    float4 wo[8];
#pragma unroll
    for (int i = 0; i < 8; ++i) wo[i] = ld4(wout + j * 32 + i * 4);
    const float bo = (br ? b_out2 : b_out1)[j];

    const float* xp = &xs[wave][h * 32];
    float acc = bo;
#pragma unroll
    for (int i = 0; i < 8; ++i) {
        float4 x = *reinterpret_cast<const float4*>(xp + i * 4);  // broadcast
        acc += x.x * wo[i].x + x.y * wo[i].y + x.z * wo[i].z + x.w * wo[i].w;
    }
    const int row = r0 + h;
    float qv = qf[(size_t)row * 32 + j];
    float* rb = res + (size_t)br * NR * 32;
    rb[(size_t)row * 32 + j] = qv + acc;
}

// ---------------------------------------------------------------------------
// K4: densify (inverted scatter). One thread per output cell; writes all 32
// channel planes coalesced, gathers the 128B res row (or zeros).
// ---------------------------------------------------------------------------
__launch_bounds__(256)
__global__ void k_densify(const int* __restrict__ grids, const float* __restrict__ res,
                          float* __restrict__ out) {
    int t = blockIdx.x * 256 + threadIdx.x;  // 0 .. 2*NB*HWC-1
    int plane = t >> 18;                     // (br*NB + b)
    int s = t & (HWC - 1);
    int gidx = grids[t];                     // query grid (set==branch)
    float4 v[8];
    if (gidx >= 0) {
        const float* rp = res + ((size_t)plane * NV + gidx) * 32;
#pragma unroll
        for (int i = 0; i < 8; ++i) v[i] = ld4(rp + i * 4);
    } else {
#pragma unroll
        for (int i = 0; i < 8; ++i) v[i] = make_float4(0.f, 0.f, 0.f, 0.f);
    }
    float* ob = out + (size_t)plane * 32 * HWC + s;
#pragma unroll
    for (int i = 0; i < 8; ++i) {
        ob[(size_t)(4 * i + 0) * HWC] = v[i].x;
        ob[(size_t)(4 * i + 1) * HWC] = v[i].y;
        ob[(size_t)(4 * i + 2) * HWC] = v[i].z;
        ob[(size_t)(4 * i + 3) * HWC] = v[i].w;
    }
}

// ---------------------------------------------------------------------------
extern "C" void kernel_launch(void* const* d_in, const int* in_sizes, int n_in,
                              void* d_out, int out_size, void* d_ws, size_t ws_size,
                              hipStream_t stream) {
    const float* li_feats = (const float*)d_in[0];
    const int*   li_coors = (const int*)d_in[1];
    const float* ra_feats = (const float*)d_in[2];
    const int*   ra_coors = (const int*)d_in[3];
    const float* w_qkv1 = (const float*)d_in[4];
    const float* b_qkv1 = (const float*)d_in[5];
    const float* w_out1 = (const float*)d_in[6];
    const float* b_out1 = (const float*)d_in[7];
    const float* w_qkv2 = (const float*)d_in[8];
    const float* b_qkv2 = (const float*)d_in[9];
    const float* w_out2 = (const float*)d_in[10];
    const float* b_out2 = (const float*)d_in[11];
    float* out = (float*)d_out;

    char* ws = (char*)d_ws;
    size_t off = 0;
    int*      grids = (int*)(ws + off);      off += (size_t)2 * NB * HWC * 4;  // 8 MB
    uint32*   KV    = (uint32*)(ws + off);   off += (size_t)NQ * 32 * 4;       // 51.2 MB (packed bf16 K|V)
    float*    res   = (float*)(ws + off);    off += (size_t)NQ * 32 * 4;       // 51.2 MB fp32
    ushort16* Qbuf  = (ushort16*)(ws + off); off += (size_t)NQ * 32 * 2;       // 25.6 MB bf16
    ushort16* obuf  = (ushort16*)(ws + off); off += (size_t)NQ * 32 * 2;       // 25.6 MB bf16
    int*      nbr   = (int*)(ws + off);      off += (size_t)NQ * 12 * 4;       // 19.2 MB

    k_fill<<<2048, 256, 0, stream>>>((int4*)grids);

    k_grid<<<(NQ + 255) / 256, 256, 0, stream>>>(li_coors, ra_coors, grids);

    // one wave per row-pair: NR/2 waves per f -> NR/8 blocks per f
    k_proj_all<<<dim3(NR / 8, 2), 256, 0, stream>>>(
        li_feats, ra_feats, w_qkv1, b_qkv1, w_qkv2, b_qkv2, Qbuf, KV);

    k_nbr<<<(NQ + 255) / 256, 256, 0, stream>>>(li_coors, ra_coors, grids, nbr);

    k_attn<<<NQ / 32, 256, 0, stream>>>(nbr, Qbuf, KV, b_qkv1, b_qkv2, obuf);

    k_outproj<<<dim3(NR / 8, 2), 256, 0, stream>>>(li_feats, ra_feats,
                                                   w_out1, b_out1, w_out2, b_out2, obuf, res);

    k_densify<<<(2 * NB * HWC) / 256, 256, 0, stream>>>(grids, res, out);
}

// Round 10
// 330.159 us; speedup vs baseline: 2.6099x; 2.6099x over previous
//
#include <hip/hip_runtime.h>

#define HH 512
#define WW 512
#define HWC (HH * WW)          // 262144 = 2^18
#define NV 50000
#define NB 4
#define NR (NB * NV)           // 200000 rows per branch
#define NQ (2 * NR)            // 400000 total queries

typedef unsigned int uint32;
typedef unsigned short ushort16;

static __device__ __forceinline__ float4 ld4(const float* p) {
    return *reinterpret_cast<const float4*>(p);
}
// round-to-nearest-even f32 -> bf16 (as low 16 bits)
static __device__ __forceinline__ uint32 bf16rne(float x) {
    uint32 u = __float_as_uint(x);
    return (u + 0x7FFFu + ((u >> 16) & 1u)) >> 16;
}
static __device__ __forceinline__ float bf16f(uint32 h) {
    return __uint_as_float(h << 16);
}

// Sum across each 16-lane row via DPP (VALU pipe, no LDS).
static __device__ __forceinline__ float red16(float x) {
    float t;
    t = __int_as_float(__builtin_amdgcn_update_dpp(0, __float_as_int(x), 0xB1, 0xF, 0xF, true));  // quad_perm(1,0,3,2)
    x += t;
    t = __int_as_float(__builtin_amdgcn_update_dpp(0, __float_as_int(x), 0x4E, 0xF, 0xF, true));  // quad_perm(2,3,0,1)
    x += t;
    t = __int_as_float(__builtin_amdgcn_update_dpp(0, __float_as_int(x), 0x141, 0xF, 0xF, true)); // row_half_mirror
    x += t;
    t = __int_as_float(__builtin_amdgcn_update_dpp(0, __float_as_int(x), 0x140, 0xF, 0xF, true)); // row_mirror
    x += t;
    return x;
}

// ---------------------------------------------------------------------------
// K0: fast -1 fill of the grids buffer.
// ---------------------------------------------------------------------------
__global__ void k_fill(int4* __restrict__ p) {
    const int total = 2 * NB * HWC / 4;
    const int stride = gridDim.x * blockDim.x;
    const int4 v = make_int4(-1, -1, -1, -1);
    for (int i = blockIdx.x * blockDim.x + threadIdx.x; i < total; i += stride)
        p[i] = v;
}

// ---------------------------------------------------------------------------
// K1: scatter voxel indices into dense coord->index grids
// grids layout: [set(0=li,1=ra)][b][HWC], pre-filled with -1
// ---------------------------------------------------------------------------
__global__ void k_grid(const int* __restrict__ li_coors, const int* __restrict__ ra_coors,
                       int* __restrict__ grids) {
    int t = blockIdx.x * blockDim.x + threadIdx.x;
    if (t >= NQ) return;
    int set = t / NR;
    int r2 = t - set * NR;
    int b = r2 / NV;
    int n = r2 - b * NV;
    const int* co = (set == 0 ? li_coors : ra_coors) + (size_t)(b * NV + n) * 2;
    grids[(set * NB + b) * HWC + co[0] * WW + co[1]] = n;
}

// ---------------------------------------------------------------------------
// K2: combined projection, wave-loop + 2-deep software pipeline.
// Round-9 lesson: one-shot re-fetches 24.5KB of weights per wave (541us).
// Round-8 lesson: single-buffered LDS tile serializes load->compute (159us).
// Here: weights stay VGPR-resident across ~8 iters AND the row tile is
// double-buffered so the next global load overlaps the current compute.
// Outputs bf16: Qbuf[f] (ushort) and packed KV[f^1] (uint: K low16, V high16).
// ---------------------------------------------------------------------------
__launch_bounds__(256)
__global__ void k_proj_all(const float* __restrict__ li_feats, const float* __restrict__ ra_feats,
                           const float* __restrict__ w_qkv1, const float* __restrict__ b_qkv1,
                           const float* __restrict__ w_qkv2, const float* __restrict__ b_qkv2,
                           ushort16* __restrict__ Qbuf, uint32* __restrict__ KV) {
    const int f = blockIdx.y;
    const float* feats = f ? ra_feats : li_feats;
    const float* wq_g  = f ? w_qkv2 : w_qkv1;   // queries of branch f
    const float* bq_g  = f ? b_qkv2 : b_qkv1;
    const float* wkv_g = f ? w_qkv1 : w_qkv2;   // keys/values consumed by branch f^1
    const float* bkv_g = f ? b_qkv1 : b_qkv2;

    __shared__ float xs[4][2][64];
    const int wave = threadIdx.x >> 6;
    const int l    = threadIdx.x & 63;
    const int h    = l >> 5;         // which row of the pair
    const int j    = l & 31;         // output column

    const int gw = blockIdx.x * 4 + wave;          // global wave id
    const int gs = gridDim.x * 4;                  // wave stride

    int r0 = gw * 2;
    float xreg = feats[(size_t)r0 * 32 + l];       // prefetch pair 0 first

    float4 wq[8], wk[8], wv[8];
#pragma unroll
    for (int i = 0; i < 8; ++i) {
        wq[i] = ld4(wq_g  + j * 32 + i * 4);
        wk[i] = ld4(wkv_g + (32 + j) * 32 + i * 4);
        wv[i] = ld4(wkv_g + (64 + j) * 32 + i * 4);
    }
    const float bq = bq_g[j], bk = bkv_g[32 + j], bv = bkv_g[64 + j];

    ushort16* Qb = Qbuf + (size_t)f * NR * 32;
    uint32*  KVb = KV + (size_t)(f ^ 1) * NR * 32;

    int cur = 0;
    while (r0 < NR) {
        xs[wave][cur][l] = xreg;                   // stage current pair
        const int rn = r0 + gs * 2;
        if (rn < NR) xreg = feats[(size_t)rn * 32 + l];  // issue next load NOW

        const float* xp = &xs[wave][cur][h * 32];
        float aq = bq, ak = bk, av = bv;
#pragma unroll
        for (int i = 0; i < 8; ++i) {
            float4 x = *reinterpret_cast<const float4*>(xp + i * 4);  // broadcast
            aq += x.x * wq[i].x + x.y * wq[i].y + x.z * wq[i].z + x.w * wq[i].w;
            ak += x.x * wk[i].x + x.y * wk[i].y + x.z * wk[i].z + x.w * wk[i].w;
            av += x.x * wv[i].x + x.y * wv[i].y + x.z * wv[i].z + x.w * wv[i].w;
        }
        const int row = r0 + h;
        Qb[(size_t)row * 32 + j] = (ushort16)bf16rne(aq);
        KVb[(size_t)row * 32 + j] = bf16rne(ak) | (bf16rne(av) << 16);
        r0 = rn;
        cur ^= 1;
    }
}

// ---------------------------------------------------------------------------
// K3a: neighbor resolve. 1 thread per query; 9 independent grid loads.
// Writes [q][12]: idx0..8 (clamped), mask, pad, pad.
// ---------------------------------------------------------------------------
__global__ void k_nbr(const int* __restrict__ li_coors, const int* __restrict__ ra_coors,
                      const int* __restrict__ grids, int* __restrict__ nbr) {
    int q = blockIdx.x * 256 + threadIdx.x;
    if (q >= NQ) return;
    int br  = (q >= NR) ? 1 : 0;
    int rem = q - br * NR;
    int b   = rem / NV;
    const int* qc = br ? ra_coors : li_coors;
    const int* kvgrid = grids + ((br ^ 1) * NB + b) * HWC;
    const int2 rc = *reinterpret_cast<const int2*>(qc + (size_t)rem * 2);

    const int drs[9] = {0, -1, 1, 0, -1, 1, 0, -1, 1};
    const int dcs[9] = {0, 0, 0, 1, 1, 1, -1, -1, -1};
    int v[9];
    int mask = 0;
#pragma unroll
    for (int k = 0; k < 9; ++k) {
        int rr = rc.x + drs[k], cc = rc.y + dcs[k];
        bool valid = ((unsigned)rr < HH) & ((unsigned)cc < WW);
        int raw = kvgrid[valid ? rr * WW + cc : 0];
        int id = valid ? raw : -1;
        mask |= (int)(id >= 0) << k;
        v[k] = id > 0 ? id : 0;
    }
    int4* np = reinterpret_cast<int4*>(nbr + (size_t)q * 12);
    np[0] = make_int4(v[0], v[1], v[2], v[3]);
    np[1] = make_int4(v[4], v[5], v[6], v[7]);
    np[2] = make_int4(v[8], mask, 0, 0);
}

// ---------------------------------------------------------------------------
// K3b: slim attention core. 32 lanes per query, 4 queries per lane-group
// (36 outstanding u32 gathers/lane). bf16 Q/K/V; writes bf16 o.
// ---------------------------------------------------------------------------
__launch_bounds__(256)
__global__ void k_attn(const int* __restrict__ nbr, const ushort16* __restrict__ Qbuf,
                       const uint32* __restrict__ KV,
                       const float* __restrict__ b_qkv1, const float* __restrict__ b_qkv2,
                       ushort16* __restrict__ obuf) {
    const int g = threadIdx.x >> 5;
    const int j = threadIdx.x & 31;
    const int q0 = (blockIdx.x * 8 + g) * 4;   // 4 queries, never straddle b/br
    const int br  = (q0 >= NR) ? 1 : 0;
    const int rem = q0 - br * NR;
    const int bb  = rem / NV;
    const uint32* KVbb = KV + ((size_t)br * NR + (size_t)bb * NV) * 32;
    const float* bqkv = br ? b_qkv2 : b_qkv1;

    int4 a0[4], a1[4], a2[4];
#pragma unroll
    for (int u = 0; u < 4; ++u) {
        const int4* np = reinterpret_cast<const int4*>(nbr + (size_t)(q0 + u) * 12);
        a0[u] = np[0]; a1[u] = np[1]; a2[u] = np[2];
    }
    float Qf[4];
#pragma unroll
    for (int u = 0; u < 4; ++u) Qf[u] = bf16f(Qbuf[(size_t)(q0 + u) * 32 + j]);
    const float bk = bqkv[32 + j], bv = bqkv[64 + j];

    // batched gathers: 36 independent u32 loads
    uint32 kvw[4][9];
#pragma unroll
    for (int u = 0; u < 4; ++u) {
        int id[9] = {a0[u].x, a0[u].y, a0[u].z, a0[u].w,
                     a1[u].x, a1[u].y, a1[u].z, a1[u].w, a2[u].x};
#pragma unroll
        for (int k = 0; k < 9; ++k)
            kvw[u][k] = KVbb[(size_t)id[k] * 32 + j];
    }

#pragma unroll
    for (int u = 0; u < 4; ++u) {
        const int mask = a2[u].y;
        float sc[9];
#pragma unroll
        for (int k = 0; k < 9; ++k) {
            float kk = ((mask >> k) & 1) ? __uint_as_float(kvw[u][k] << 16) : bk;
            sc[k] = red16(Qf[u] * kk) * 0.25f;  // 1/sqrt(HD=16)
        }
        float m = sc[0];
#pragma unroll
        for (int k = 1; k < 9; ++k) m = fmaxf(m, sc[k]);
        float sum = 0.f, o = 0.f;
#pragma unroll
        for (int k = 0; k < 9; ++k) {
            float e = __expf(sc[k] - m);
            float vv = ((mask >> k) & 1) ? __uint_as_float(kvw[u][k] & 0xFFFF0000u) : bv;
            sum += e;
            o += e * vv;
        }
        obuf[(size_t)(q0 + u) * 32 + j] = (ushort16)bf16rne(o / sum);
    }
}

// ---------------------------------------------------------------------------
// K3c: out-projection + residual, wave-loop + 2-deep pipeline (same scheme
// as K2). blockIdx.y = branch. Prefetches next obuf row-pair AND next
// residual element while computing the current pair.
// ---------------------------------------------------------------------------
__launch_bounds__(256)
__global__ void k_outproj(const float* __restrict__ li_feats, const float* __restrict__ ra_feats,
                          const float* __restrict__ w_out1, const float* __restrict__ b_out1,
                          const float* __restrict__ w_out2, const float* __restrict__ b_out2,
                          const ushort16* __restrict__ obuf, float* __restrict__ res) {
    const int br = blockIdx.y;
    const float* wout   = br ? w_out2 : w_out1;
    const float* qfeats = br ? ra_feats : li_feats;

    __shared__ float xs[4][2][64];
    const int wave = threadIdx.x >> 6;
    const int l    = threadIdx.x & 63;
    const int h    = l >> 5;
    const int j    = l & 31;

    const int gw = blockIdx.x * 4 + wave;
    const int gs = gridDim.x * 4;

    const ushort16* ob = obuf + (size_t)br * NR * 32;
    float* rb = res + (size_t)br * NR * 32;

    int r0 = gw * 2;
    float xreg = bf16f(ob[(size_t)r0 * 32 + l]);       // prefetch o pair 0
    float qreg = qfeats[(size_t)(r0 + h) * 32 + j];    // prefetch residual 0

    float4 wo[8];
#pragma unroll
    for (int i = 0; i < 8; ++i) wo[i] = ld4(wout + j * 32 + i * 4);
    const float bo = (br ? b_out2 : b_out1)[j];

    int cur = 0;
    while (r0 < NR) {
        xs[wave][cur][l] = xreg;
        const int rn = r0 + gs * 2;
        const float qcur = qreg;
        if (rn < NR) {
            xreg = bf16f(ob[(size_t)rn * 32 + l]);     // issue next loads NOW
            qreg = qfeats[(size_t)(rn + h) * 32 + j];
        }
        const float* xp = &xs[wave][cur][h * 32];
        float acc = bo;
#pragma unroll
        for (int i = 0; i < 8; ++i) {
            float4 x = *reinterpret_cast<const float4*>(xp + i * 4);  // broadcast
            acc += x.x * wo[i].x + x.y * wo[i].y + x.z * wo[i].z + x.w * wo[i].w;
        }
        rb[(size_t)(r0 + h) * 32 + j] = qcur + acc;
        r0 = rn;
        cur ^= 1;
    }
}

// ---------------------------------------------------------------------------
// K4: densify (inverted scatter). One thread per output cell; writes all 32
// channel planes coalesced, gathers the 128B res row (or zeros).
// ---------------------------------------------------------------------------
__launch_bounds__(256)
__global__ void k_densify(const int* __restrict__ grids, const float* __restrict__ res,
                          float* __restrict__ out) {
    int t = blockIdx.x * 256 + threadIdx.x;  // 0 .. 2*NB*HWC-1
    int plane = t >> 18;                     // (br*NB + b)
    int s = t & (HWC - 1);
    int gidx = grids[t];                     // query grid (set==branch)
    float4 v[8];
    if (gidx >= 0) {
        const float* rp = res + ((size_t)plane * NV + gidx) * 32;
#pragma unroll
        for (int i = 0; i < 8; ++i) v[i] = ld4(rp + i * 4);
    } else {
#pragma unroll
        for (int i = 0; i < 8; ++i) v[i] = make_float4(0.f, 0.f, 0.f, 0.f);
    }
    float* ob = out + (size_t)plane * 32 * HWC + s;
#pragma unroll
    for (int i = 0; i < 8; ++i) {
        ob[(size_t)(4 * i + 0) * HWC] = v[i].x;
        ob[(size_t)(4 * i + 1) * HWC] = v[i].y;
        ob[(size_t)(4 * i + 2) * HWC] = v[i].z;
        ob[(size_t)(4 * i + 3) * HWC] = v[i].w;
    }
}

// ---------------------------------------------------------------------------
extern "C" void kernel_launch(void* const* d_in, const int* in_sizes, int n_in,
                              void* d_out, int out_size, void* d_ws, size_t ws_size,
                              hipStream_t stream) {
    const float* li_feats = (const float*)d_in[0];
    const int*   li_coors = (const int*)d_in[1];
    const float* ra_feats = (const float*)d_in[2];
    const int*   ra_coors = (const int*)d_in[3];
    const float* w_qkv1 = (const float*)d_in[4];
    const float* b_qkv1 = (const float*)d_in[5];
    const float* w_out1 = (const float*)d_in[6];
    const float* b_out1 = (const float*)d_in[7];
    const float* w_qkv2 = (const float*)d_in[8];
    const float* b_qkv2 = (const float*)d_in[9];
    const float* w_out2 = (const float*)d_in[10];
    const float* b_out2 = (const float*)d_in[11];
    float* out = (float*)d_out;

    char* ws = (char*)d_ws;
    size_t off = 0;
    int*      grids = (int*)(ws + off);      off += (size_t)2 * NB * HWC * 4;  // 8 MB
    uint32*   KV    = (uint32*)(ws + off);   off += (size_t)NQ * 32 * 4;       // 51.2 MB (packed bf16 K|V)
    float*    res   = (float*)(ws + off);    off += (size_t)NQ * 32 * 4;       // 51.2 MB fp32
    ushort16* Qbuf  = (ushort16*)(ws + off); off += (size_t)NQ * 32 * 2;       // 25.6 MB bf16
    ushort16* obuf  = (ushort16*)(ws + off); off += (size_t)NQ * 32 * 2;       // 25.6 MB bf16
    int*      nbr   = (int*)(ws + off);      off += (size_t)NQ * 12 * 4;       // 19.2 MB

    k_fill<<<2048, 256, 0, stream>>>((int4*)grids);

    k_grid<<<(NQ + 255) / 256, 256, 0, stream>>>(li_coors, ra_coors, grids);

    k_proj_all<<<dim3(3200, 2), 256, 0, stream>>>(
        li_feats, ra_feats, w_qkv1, b_qkv1, w_qkv2, b_qkv2, Qbuf, KV);

    k_nbr<<<(NQ + 255) / 256, 256, 0, stream>>>(li_coors, ra_coors, grids, nbr);

    k_attn<<<NQ / 32, 256, 0, stream>>>(nbr, Qbuf, KV, b_qkv1, b_qkv2, obuf);

    k_outproj<<<dim3(3200, 2), 256, 0, stream>>>(li_feats, ra_feats,
                                                 w_out1, b_out1, w_out2, b_out2, obuf, res);

    k_densify<<<(2 * NB * HWC) / 256, 256, 0, stream>>>(grids, res, out);
}

// Round 11
// 310.819 us; speedup vs baseline: 2.7723x; 1.0622x over previous
//
#include <hip/hip_runtime.h>

#define HH 512
#define WW 512
#define HWC (HH * WW)          // 262144 = 2^18
#define NV 50000
#define NB 4
#define NR (NB * NV)           // 200000 rows per branch
#define NQ (2 * NR)            // 400000 total queries

typedef unsigned int uint32;
typedef unsigned short ushort16;

static __device__ __forceinline__ float4 ld4(const float* p) {
    return *reinterpret_cast<const float4*>(p);
}
// round-to-nearest-even f32 -> bf16 (as low 16 bits)
static __device__ __forceinline__ uint32 bf16rne(float x) {
    uint32 u = __float_as_uint(x);
    return (u + 0x7FFFu + ((u >> 16) & 1u)) >> 16;
}
static __device__ __forceinline__ float bf16f(uint32 h) {
    return __uint_as_float(h << 16);
}

// Sum across each 16-lane row via DPP (VALU pipe, no LDS).
static __device__ __forceinline__ float red16(float x) {
    float t;
    t = __int_as_float(__builtin_amdgcn_update_dpp(0, __float_as_int(x), 0xB1, 0xF, 0xF, true));  // quad_perm(1,0,3,2)
    x += t;
    t = __int_as_float(__builtin_amdgcn_update_dpp(0, __float_as_int(x), 0x4E, 0xF, 0xF, true));  // quad_perm(2,3,0,1)
    x += t;
    t = __int_as_float(__builtin_amdgcn_update_dpp(0, __float_as_int(x), 0x141, 0xF, 0xF, true)); // row_half_mirror
    x += t;
    t = __int_as_float(__builtin_amdgcn_update_dpp(0, __float_as_int(x), 0x140, 0xF, 0xF, true)); // row_mirror
    x += t;
    return x;
}

// ---------------------------------------------------------------------------
// K0: fast -1 fill of the grids buffer.
// ---------------------------------------------------------------------------
__global__ void k_fill(int4* __restrict__ p) {
    const int total = 2 * NB * HWC / 4;
    const int stride = gridDim.x * blockDim.x;
    const int4 v = make_int4(-1, -1, -1, -1);
    for (int i = blockIdx.x * blockDim.x + threadIdx.x; i < total; i += stride)
        p[i] = v;
}

// ---------------------------------------------------------------------------
// K1: scatter voxel indices into dense coord->index grids
// grids layout: [set(0=li,1=ra)][b][HWC], pre-filled with -1
// ---------------------------------------------------------------------------
__global__ void k_grid(const int* __restrict__ li_coors, const int* __restrict__ ra_coors,
                       int* __restrict__ grids) {
    int t = blockIdx.x * blockDim.x + threadIdx.x;
    if (t >= NQ) return;
    int set = t / NR;
    int r2 = t - set * NR;
    int b = r2 / NV;
    int n = r2 - b * NV;
    const int* co = (set == 0 ? li_coors : ra_coors) + (size_t)(b * NV + n) * 2;
    grids[(set * NB + b) * HWC + co[0] * WW + co[1]] = n;
}

// ---------------------------------------------------------------------------
// K2: K|V projection only (Q is fused into k_attn now). Wave-loop + 2-deep
// software pipeline (round-10 structure). blockIdx.y = f (feats tensor).
// Output: packed KV[f^1] (uint: K low16, V high16), row = 32 uints = 128B.
// ---------------------------------------------------------------------------
__launch_bounds__(256)
__global__ void k_proj_kv(const float* __restrict__ li_feats, const float* __restrict__ ra_feats,
                          const float* __restrict__ w_qkv1, const float* __restrict__ b_qkv1,
                          const float* __restrict__ w_qkv2, const float* __restrict__ b_qkv2,
                          uint32* __restrict__ KV) {
    const int f = blockIdx.y;
    const float* feats = f ? ra_feats : li_feats;
    const float* wkv_g = f ? w_qkv1 : w_qkv2;   // weights of branch f^1
    const float* bkv_g = f ? b_qkv1 : b_qkv2;

    __shared__ float xs[4][2][64];
    const int wave = threadIdx.x >> 6;
    const int l    = threadIdx.x & 63;
    const int h    = l >> 5;         // which row of the pair
    const int j    = l & 31;         // output column

    const int gw = blockIdx.x * 4 + wave;          // global wave id
    const int gs = gridDim.x * 4;                  // wave stride

    int r0 = gw * 2;
    float xreg = feats[(size_t)r0 * 32 + l];       // prefetch pair 0 first

    float4 wk[8], wv[8];
#pragma unroll
    for (int i = 0; i < 8; ++i) {
        wk[i] = ld4(wkv_g + (32 + j) * 32 + i * 4);
        wv[i] = ld4(wkv_g + (64 + j) * 32 + i * 4);
    }
    const float bk = bkv_g[32 + j], bv = bkv_g[64 + j];

    uint32* KVb = KV + (size_t)(f ^ 1) * NR * 32;

    int cur = 0;
    while (r0 < NR) {
        xs[wave][cur][l] = xreg;                   // stage current pair
        const int rn = r0 + gs * 2;
        if (rn < NR) xreg = feats[(size_t)rn * 32 + l];  // issue next load NOW

        const float* xp = &xs[wave][cur][h * 32];
        float ak = bk, av = bv;
#pragma unroll
        for (int i = 0; i < 8; ++i) {
            float4 x = *reinterpret_cast<const float4*>(xp + i * 4);  // broadcast
            ak += x.x * wk[i].x + x.y * wk[i].y + x.z * wk[i].z + x.w * wk[i].w;
            av += x.x * wv[i].x + x.y * wv[i].y + x.z * wv[i].z + x.w * wv[i].w;
        }
        KVb[(size_t)(r0 + h) * 32 + j] = bf16rne(ak) | (bf16rne(av) << 16);
        r0 = rn;
        cur ^= 1;
    }
}

// ---------------------------------------------------------------------------
// K3a: neighbor resolve. 1 thread per query; 9 independent grid loads.
// Writes [q][12]: idx0..8 (clamped), mask, pad, pad.
// ---------------------------------------------------------------------------
__global__ void k_nbr(const int* __restrict__ li_coors, const int* __restrict__ ra_coors,
                      const int* __restrict__ grids, int* __restrict__ nbr) {
    int q = blockIdx.x * 256 + threadIdx.x;
    if (q >= NQ) return;
    int br  = (q >= NR) ? 1 : 0;
    int rem = q - br * NR;
    int b   = rem / NV;
    const int* qc = br ? ra_coors : li_coors;
    const int* kvgrid = grids + ((br ^ 1) * NB + b) * HWC;
    const int2 rc = *reinterpret_cast<const int2*>(qc + (size_t)rem * 2);

    const int drs[9] = {0, -1, 1, 0, -1, 1, 0, -1, 1};
    const int dcs[9] = {0, 0, 0, 1, 1, 1, -1, -1, -1};
    int v[9];
    int mask = 0;
#pragma unroll
    for (int k = 0; k < 9; ++k) {
        int rr = rc.x + drs[k], cc = rc.y + dcs[k];
        bool valid = ((unsigned)rr < HH) & ((unsigned)cc < WW);
        int raw = kvgrid[valid ? rr * WW + cc : 0];
        int id = valid ? raw : -1;
        mask |= (int)(id >= 0) << k;
        v[k] = id > 0 ? id : 0;
    }
    int4* np = reinterpret_cast<int4*>(nbr + (size_t)q * 12);
    np[0] = make_int4(v[0], v[1], v[2], v[3]);
    np[1] = make_int4(v[4], v[5], v[6], v[7]);
    np[2] = make_int4(v[8], mask, 0, 0);
}

// ---------------------------------------------------------------------------
// K3b: FUSED attention core: Q-proj + attention + out-proj + residual.
// 32 lanes per query, 4 queries per lane-group. Per query:
//   - feats row loaded once (Q input AND residual), staged to LDS
//   - 36 KV gathers issued before Q-proj VALU work (latency overlap)
//   - o row bounced through LDS (intra-wave, no barrier) for out-proj
// wq regs die before wout is loaded (register discipline, round-2 lesson).
// Writes fp32 res directly. Qbuf/obuf/k_outproj deleted.
// ---------------------------------------------------------------------------
__launch_bounds__(256)
__global__ void k_attn(const int* __restrict__ nbr,
                       const float* __restrict__ li_feats, const float* __restrict__ ra_feats,
                       const float* __restrict__ w_qkv1, const float* __restrict__ b_qkv1,
                       const float* __restrict__ w_out1, const float* __restrict__ b_out1,
                       const float* __restrict__ w_qkv2, const float* __restrict__ b_qkv2,
                       const float* __restrict__ w_out2, const float* __restrict__ b_out2,
                       const uint32* __restrict__ KV, float* __restrict__ res) {
    __shared__ float xs[8][4][32];     // feats rows
    __shared__ float os[8][4][32];     // attention outputs
    const int g = threadIdx.x >> 5;
    const int j = threadIdx.x & 31;
    const int q0 = (blockIdx.x * 8 + g) * 4;   // 4 queries, never straddle b/br
    const int br  = (q0 >= NR) ? 1 : 0;
    const int rem = q0 - br * NR;
    const int bb  = rem / NV;
    const float* feats = br ? ra_feats : li_feats;
    const float* wqkv  = br ? w_qkv2 : w_qkv1;
    const float* bqkv  = br ? b_qkv2 : b_qkv1;
    const float* wout  = br ? w_out2 : w_out1;
    const float* bout  = br ? b_out2 : b_out1;
    const uint32* KVbb = KV + ((size_t)br * NR + (size_t)bb * NV) * 32;

    // ---- nbr metadata (uniform per group -> broadcast loads) ----------
    int4 a0[4], a1[4], a2[4];
#pragma unroll
    for (int u = 0; u < 4; ++u) {
        const int4* np = reinterpret_cast<const int4*>(nbr + (size_t)(q0 + u) * 12);
        a0[u] = np[0]; a1[u] = np[1]; a2[u] = np[2];
    }

    // ---- feats rows: Q input + residual, staged to LDS ---------------
    float fr[4];
#pragma unroll
    for (int u = 0; u < 4; ++u) {
        fr[u] = feats[(size_t)(rem + u) * 32 + j];
        xs[g][u][j] = fr[u];
    }

    // ---- 36 KV gathers issued now; Q-proj below hides their latency --
    uint32 kvw[4][9];
#pragma unroll
    for (int u = 0; u < 4; ++u) {
        int id[9] = {a0[u].x, a0[u].y, a0[u].z, a0[u].w,
                     a1[u].x, a1[u].y, a1[u].z, a1[u].w, a2[u].x};
#pragma unroll
        for (int k = 0; k < 9; ++k)
            kvw[u][k] = KVbb[(size_t)id[k] * 32 + j];
    }

    // ---- Q projection (wq regs die after this block) ------------------
    const float bq = bqkv[j], bk = bqkv[32 + j], bv = bqkv[64 + j];
    float Qf[4] = {bq, bq, bq, bq};
    {
#pragma unroll
        for (int i = 0; i < 8; ++i) {
            float4 w = ld4(wqkv + j * 32 + i * 4);
#pragma unroll
            for (int u = 0; u < 4; ++u) {
                float4 x = *reinterpret_cast<const float4*>(&xs[g][u][i * 4]);
                Qf[u] += x.x * w.x + x.y * w.y + x.z * w.z + x.w * w.w;
            }
        }
    }

    // ---- scores + softmax + weighted V --------------------------------
#pragma unroll
    for (int u = 0; u < 4; ++u) {
        const int mask = a2[u].y;
        float sc[9];
#pragma unroll
        for (int k = 0; k < 9; ++k) {
            float kk = ((mask >> k) & 1) ? __uint_as_float(kvw[u][k] << 16) : bk;
            sc[k] = red16(Qf[u] * kk) * 0.25f;  // 1/sqrt(HD=16)
        }
        float m = sc[0];
#pragma unroll
        for (int k = 1; k < 9; ++k) m = fmaxf(m, sc[k]);
        float sum = 0.f, o = 0.f;
#pragma unroll
        for (int k = 0; k < 9; ++k) {
            float e = __expf(sc[k] - m);
            float vv = ((mask >> k) & 1) ? __uint_as_float(kvw[u][k] & 0xFFFF0000u) : bv;
            sum += e;
            o += e * vv;
        }
        os[g][u][j] = o / sum;   // intra-wave producer/consumer: no barrier
    }

    // ---- out-projection + residual ------------------------------------
    const float bo = bout[j];
    float outv[4] = {bo, bo, bo, bo};
#pragma unroll
    for (int i = 0; i < 8; ++i) {
        float4 w = ld4(wout + j * 32 + i * 4);
#pragma unroll
        for (int u = 0; u < 4; ++u) {
            float4 x = *reinterpret_cast<const float4*>(&os[g][u][i * 4]);
            outv[u] += x.x * w.x + x.y * w.y + x.z * w.z + x.w * w.w;
        }
    }
#pragma unroll
    for (int u = 0; u < 4; ++u)
        res[(size_t)(q0 + u) * 32 + j] = fr[u] + outv[u];
}

// ---------------------------------------------------------------------------
// K4: densify (inverted scatter). One thread per output cell; writes all 32
// channel planes coalesced, gathers the 128B res row (or zeros).
// ---------------------------------------------------------------------------
__launch_bounds__(256)
__global__ void k_densify(const int* __restrict__ grids, const float* __restrict__ res,
                          float* __restrict__ out) {
    int t = blockIdx.x * 256 + threadIdx.x;  // 0 .. 2*NB*HWC-1
    int plane = t >> 18;                     // (br*NB + b)
    int s = t & (HWC - 1);
    int gidx = grids[t];                     // query grid (set==branch)
    float4 v[8];
    if (gidx >= 0) {
        const float* rp = res + ((size_t)plane * NV + gidx) * 32;
#pragma unroll
        for (int i = 0; i < 8; ++i) v[i] = ld4(rp + i * 4);
    } else {
#pragma unroll
        for (int i = 0; i < 8; ++i) v[i] = make_float4(0.f, 0.f, 0.f, 0.f);
    }
    float* ob = out + (size_t)plane * 32 * HWC + s;
#pragma unroll
    for (int i = 0; i < 8; ++i) {
        ob[(size_t)(4 * i + 0) * HWC] = v[i].x;
        ob[(size_t)(4 * i + 1) * HWC] = v[i].y;
        ob[(size_t)(4 * i + 2) * HWC] = v[i].z;
        ob[(size_t)(4 * i + 3) * HWC] = v[i].w;
    }
}

// ---------------------------------------------------------------------------
extern "C" void kernel_launch(void* const* d_in, const int* in_sizes, int n_in,
                              void* d_out, int out_size, void* d_ws, size_t ws_size,
                              hipStream_t stream) {
    const float* li_feats = (const float*)d_in[0];
    const int*   li_coors = (const int*)d_in[1];
    const float* ra_feats = (const float*)d_in[2];
    const int*   ra_coors = (const int*)d_in[3];
    const float* w_qkv1 = (const float*)d_in[4];
    const float* b_qkv1 = (const float*)d_in[5];
    const float* w_out1 = (const float*)d_in[6];
    const float* b_out1 = (const float*)d_in[7];
    const float* w_qkv2 = (const float*)d_in[8];
    const float* b_qkv2 = (const float*)d_in[9];
    const float* w_out2 = (const float*)d_in[10];
    const float* b_out2 = (const float*)d_in[11];
    float* out = (float*)d_out;

    char* ws = (char*)d_ws;
    size_t off = 0;
    int*    grids = (int*)(ws + off);    off += (size_t)2 * NB * HWC * 4;  // 8 MB
    uint32* KV    = (uint32*)(ws + off); off += (size_t)NQ * 32 * 4;       // 51.2 MB (packed bf16 K|V)
    float*  res   = (float*)(ws + off);  off += (size_t)NQ * 32 * 4;       // 51.2 MB fp32
    int*    nbr   = (int*)(ws + off);    off += (size_t)NQ * 12 * 4;       // 19.2 MB

    k_fill<<<2048, 256, 0, stream>>>((int4*)grids);

    k_grid<<<(NQ + 255) / 256, 256, 0, stream>>>(li_coors, ra_coors, grids);

    k_proj_kv<<<dim3(3200, 2), 256, 0, stream>>>(
        li_feats, ra_feats, w_qkv1, b_qkv1, w_qkv2, b_qkv2, KV);

    k_nbr<<<(NQ + 255) / 256, 256, 0, stream>>>(li_coors, ra_coors, grids, nbr);

    k_attn<<<NQ / 32, 256, 0, stream>>>(
        nbr, li_feats, ra_feats,
        w_qkv1, b_qkv1, w_out1, b_out1,
        w_qkv2, b_qkv2, w_out2, b_out2,
        KV, res);

    k_densify<<<(2 * NB * HWC) / 256, 256, 0, stream>>>(grids, res, out);
}

// Round 12
// 287.541 us; speedup vs baseline: 2.9967x; 1.0810x over previous
//
#include <hip/hip_runtime.h>

#define HH 512
#define WW 512
#define HWC (HH * WW)          // 262144 = 2^18
#define NV 50000
#define NB 4
#define NR (NB * NV)           // 200000 rows per branch
#define NQ (2 * NR)            // 400000 total queries
#define KVROWS (NR + 1)        // +1 dummy bias row per branch

typedef unsigned int uint32;

static __device__ __forceinline__ float4 ld4(const float* p) {
    return *reinterpret_cast<const float4*>(p);
}
// round-to-nearest-even f32 -> bf16 (as low 16 bits)
static __device__ __forceinline__ uint32 bf16rne(float x) {
    uint32 u = __float_as_uint(x);
    return (u + 0x7FFFu + ((u >> 16) & 1u)) >> 16;
}

// Sum across each 16-lane row via DPP (VALU pipe, no LDS).
static __device__ __forceinline__ float red16(float x) {
    float t;
    t = __int_as_float(__builtin_amdgcn_update_dpp(0, __float_as_int(x), 0xB1, 0xF, 0xF, true));  // quad_perm(1,0,3,2)
    x += t;
    t = __int_as_float(__builtin_amdgcn_update_dpp(0, __float_as_int(x), 0x4E, 0xF, 0xF, true));  // quad_perm(2,3,0,1)
    x += t;
    t = __int_as_float(__builtin_amdgcn_update_dpp(0, __float_as_int(x), 0x141, 0xF, 0xF, true)); // row_half_mirror
    x += t;
    t = __int_as_float(__builtin_amdgcn_update_dpp(0, __float_as_int(x), 0x140, 0xF, 0xF, true)); // row_mirror
    x += t;
    return x;
}

// ---------------------------------------------------------------------------
// K0: fast -1 fill of the grids buffer.
// ---------------------------------------------------------------------------
__global__ void k_fill(int4* __restrict__ p) {
    const int total = 2 * NB * HWC / 4;
    const int stride = gridDim.x * blockDim.x;
    const int4 v = make_int4(-1, -1, -1, -1);
    for (int i = blockIdx.x * blockDim.x + threadIdx.x; i < total; i += stride)
        p[i] = v;
}

// ---------------------------------------------------------------------------
// K1: scatter voxel indices into dense coord->index grids
// grids layout: [set(0=li,1=ra)][b][HWC], pre-filled with -1
// ---------------------------------------------------------------------------
__global__ void k_grid(const int* __restrict__ li_coors, const int* __restrict__ ra_coors,
                       int* __restrict__ grids) {
    int t = blockIdx.x * blockDim.x + threadIdx.x;
    if (t >= NQ) return;
    int set = t / NR;
    int r2 = t - set * NR;
    int b = r2 / NV;
    int n = r2 - b * NV;
    const int* co = (set == 0 ? li_coors : ra_coors) + (size_t)(b * NV + n) * 2;
    grids[(set * NB + b) * HWC + co[0] * WW + co[1]] = n;
}

// ---------------------------------------------------------------------------
// K2: K|V projection, wave-loop + 2-deep pipeline (round-10 structure).
// blockIdx.y = f (feats tensor). Output: packed KV[f^1] (K low16, V high16),
// plane layout [KVROWS][32] u32 — row NR is the DUMMY BIAS ROW (bk|bv), so
// k_attn needs no valid-mask selects at all.
// ---------------------------------------------------------------------------
__launch_bounds__(256)
__global__ void k_proj_kv(const float* __restrict__ li_feats, const float* __restrict__ ra_feats,
                          const float* __restrict__ w_qkv1, const float* __restrict__ b_qkv1,
                          const float* __restrict__ w_qkv2, const float* __restrict__ b_qkv2,
                          uint32* __restrict__ KV) {
    const int f = blockIdx.y;
    const float* feats = f ? ra_feats : li_feats;
    const float* wkv_g = f ? w_qkv1 : w_qkv2;   // weights of branch f^1
    const float* bkv_g = f ? b_qkv1 : b_qkv2;

    __shared__ float xs[4][2][64];
    const int wave = threadIdx.x >> 6;
    const int l    = threadIdx.x & 63;
    const int h    = l >> 5;         // which row of the pair
    const int j    = l & 31;         // output column

    const int gw = blockIdx.x * 4 + wave;          // global wave id
    const int gs = gridDim.x * 4;                  // wave stride

    int r0 = gw * 2;
    float xreg = feats[(size_t)r0 * 32 + l];       // prefetch pair 0 first

    float4 wk[8], wv[8];
#pragma unroll
    for (int i = 0; i < 8; ++i) {
        wk[i] = ld4(wkv_g + (32 + j) * 32 + i * 4);
        wv[i] = ld4(wkv_g + (64 + j) * 32 + i * 4);
    }
    const float bk = bkv_g[32 + j], bv = bkv_g[64 + j];

    uint32* KVb = KV + (size_t)(f ^ 1) * KVROWS * 32;

    if (blockIdx.x == 0 && threadIdx.x < 32)       // dummy bias row
        KVb[(size_t)NR * 32 + threadIdx.x] = bf16rne(bk) | (bf16rne(bv) << 16);

    int cur = 0;
    while (r0 < NR) {
        xs[wave][cur][l] = xreg;                   // stage current pair
        const int rn = r0 + gs * 2;
        if (rn < NR) xreg = feats[(size_t)rn * 32 + l];  // issue next load NOW

        const float* xp = &xs[wave][cur][h * 32];
        float ak = bk, av = bv;
#pragma unroll
        for (int i = 0; i < 8; ++i) {
            float4 x = *reinterpret_cast<const float4*>(xp + i * 4);  // broadcast
            ak += x.x * wk[i].x + x.y * wk[i].y + x.z * wk[i].z + x.w * wk[i].w;
            av += x.x * wv[i].x + x.y * wv[i].y + x.z * wv[i].z + x.w * wv[i].w;
        }
        KVb[(size_t)(r0 + h) * 32 + j] = bf16rne(ak) | (bf16rne(av) << 16);
        r0 = rn;
        cur ^= 1;
    }
}

// ---------------------------------------------------------------------------
// K3a: neighbor resolve. 1 thread per query; 9 independent grid loads.
// Writes [q][12]: BYTE offsets into the branch KV plane (bb*NV folded in;
// invalid/empty -> dummy row NR), plus 3 pad ints.
// ---------------------------------------------------------------------------
__global__ void k_nbr(const int* __restrict__ li_coors, const int* __restrict__ ra_coors,
                      const int* __restrict__ grids, int* __restrict__ nbr) {
    int q = blockIdx.x * 256 + threadIdx.x;
    if (q >= NQ) return;
    int br  = (q >= NR) ? 1 : 0;
    int rem = q - br * NR;
    int b   = rem / NV;
    const int* qc = br ? ra_coors : li_coors;
    const int* kvgrid = grids + ((br ^ 1) * NB + b) * HWC;
    const int2 rc = *reinterpret_cast<const int2*>(qc + (size_t)rem * 2);

    const int drs[9] = {0, -1, 1, 0, -1, 1, 0, -1, 1};
    const int dcs[9] = {0, 0, 0, 1, 1, 1, -1, -1, -1};
    const int base = b * NV;
    int v[9];
#pragma unroll
    for (int k = 0; k < 9; ++k) {
        int rr = rc.x + drs[k], cc = rc.y + dcs[k];
        bool valid = ((unsigned)rr < HH) & ((unsigned)cc < WW);
        int raw = kvgrid[valid ? rr * WW + cc : 0];
        int id = valid ? raw : -1;
        v[k] = (id >= 0 ? base + id : NR) * 128;   // byte offset; dummy row if miss
    }
    int4* np = reinterpret_cast<int4*>(nbr + (size_t)q * 12);
    np[0] = make_int4(v[0], v[1], v[2], v[3]);
    np[1] = make_int4(v[4], v[5], v[6], v[7]);
    np[2] = make_int4(v[8], 0, 0, 0);
}

// ---------------------------------------------------------------------------
// K3b: FUSED attention core: Q-proj + attention + out-proj + residual.
// 32 lanes per query, 4 queries per lane-group. VALU diet (round 12):
//   - dummy bias row -> no valid-mask selects
//   - no max-subtraction (scores bounded ~|4|, exp2 overflow at 128)
//   - 0.25*log2(e) folded into Q once; exp2f == v_exp_f32 directly
//   - gathers: 32-bit byte-offset + lane j*4, single add each
// ---------------------------------------------------------------------------
__launch_bounds__(256)
__global__ void k_attn(const int* __restrict__ nbr,
                       const float* __restrict__ li_feats, const float* __restrict__ ra_feats,
                       const float* __restrict__ w_qkv1, const float* __restrict__ b_qkv1,
                       const float* __restrict__ w_out1, const float* __restrict__ b_out1,
                       const float* __restrict__ w_qkv2, const float* __restrict__ b_qkv2,
                       const float* __restrict__ w_out2, const float* __restrict__ b_out2,
                       const uint32* __restrict__ KV, float* __restrict__ res) {
    __shared__ float xs[8][4][32];     // feats rows
    __shared__ float os[8][4][32];     // attention outputs
    const int g = threadIdx.x >> 5;
    const int j = threadIdx.x & 31;
    const int q0 = (blockIdx.x * 8 + g) * 4;   // 4 queries, never straddle b/br
    const int br  = (q0 >= NR) ? 1 : 0;
    const int rem = q0 - br * NR;
    const float* feats = br ? ra_feats : li_feats;
    const float* wqkv  = br ? w_qkv2 : w_qkv1;
    const float* bqkv  = br ? b_qkv2 : b_qkv1;
    const float* wout  = br ? w_out2 : w_out1;
    const float* bout  = br ? b_out2 : b_out1;
    const char* KVbr = (const char*)(KV + (size_t)br * KVROWS * 32);

    // ---- nbr metadata (uniform per group -> broadcast loads) ----------
    int4 a0[4], a1[4], a2[4];
#pragma unroll
    for (int u = 0; u < 4; ++u) {
        const int4* np = reinterpret_cast<const int4*>(nbr + (size_t)(q0 + u) * 12);
        a0[u] = np[0]; a1[u] = np[1]; a2[u] = np[2];
    }

    // ---- feats rows: Q input + residual, staged to LDS ---------------
    float fr[4];
#pragma unroll
    for (int u = 0; u < 4; ++u) {
        fr[u] = feats[(size_t)(rem + u) * 32 + j];
        xs[g][u][j] = fr[u];
    }

    // ---- 36 KV gathers issued now; Q-proj below hides their latency --
    const int joff = j * 4;
    uint32 kvw[4][9];
#pragma unroll
    for (int u = 0; u < 4; ++u) {
        int off[9] = {a0[u].x, a0[u].y, a0[u].z, a0[u].w,
                      a1[u].x, a1[u].y, a1[u].z, a1[u].w, a2[u].x};
#pragma unroll
        for (int k = 0; k < 9; ++k)
            kvw[u][k] = *reinterpret_cast<const uint32*>(KVbr + (size_t)(unsigned)(off[k] + joff));
    }

    // ---- Q projection (wq regs die after this block) ------------------
    const float bq = bqkv[j];
    float Qf[4] = {bq, bq, bq, bq};
#pragma unroll
    for (int i = 0; i < 8; ++i) {
        float4 w = ld4(wqkv + j * 32 + i * 4);
#pragma unroll
        for (int u = 0; u < 4; ++u) {
            float4 x = *reinterpret_cast<const float4*>(&xs[g][u][i * 4]);
            Qf[u] += x.x * w.x + x.y * w.y + x.z * w.z + x.w * w.w;
        }
    }
    const float SC = 0.25f * 1.44269504f;   // 1/sqrt(16) * log2(e)
#pragma unroll
    for (int u = 0; u < 4; ++u) Qf[u] *= SC;

    // ---- scores + softmax (no max-sub, base-2) + weighted V -----------
#pragma unroll
    for (int u = 0; u < 4; ++u) {
        float sum = 0.f, o = 0.f;
#pragma unroll
        for (int k = 0; k < 9; ++k) {
            float kk = __uint_as_float(kvw[u][k] << 16);
            float e = exp2f(red16(Qf[u] * kk));
            float vv = __uint_as_float(kvw[u][k] & 0xFFFF0000u);
            sum += e;
            o += e * vv;
        }
        os[g][u][j] = o / sum;   // intra-wave producer/consumer: no barrier
    }

    // ---- out-projection + residual ------------------------------------
    const float bo = bout[j];
    float outv[4] = {bo, bo, bo, bo};
#pragma unroll
    for (int i = 0; i < 8; ++i) {
        float4 w = ld4(wout + j * 32 + i * 4);
#pragma unroll
        for (int u = 0; u < 4; ++u) {
            float4 x = *reinterpret_cast<const float4*>(&os[g][u][i * 4]);
            outv[u] += x.x * w.x + x.y * w.y + x.z * w.z + x.w * w.w;
        }
    }
#pragma unroll
    for (int u = 0; u < 4; ++u)
        res[(size_t)(q0 + u) * 32 + j] = fr[u] + outv[u];
}

// ---------------------------------------------------------------------------
// K4: densify (inverted scatter). One thread per output cell; writes all 32
// channel planes coalesced, gathers the 128B res row (or zeros).
// ---------------------------------------------------------------------------
__launch_bounds__(256)
__global__ void k_densify(const int* __restrict__ grids, const float* __restrict__ res,
                          float* __restrict__ out) {
    int t = blockIdx.x * 256 + threadIdx.x;  // 0 .. 2*NB*HWC-1
    int plane = t >> 18;                     // (br*NB + b)
    int s = t & (HWC - 1);
    int gidx = grids[t];                     // query grid (set==branch)
    float4 v[8];
    if (gidx >= 0) {
        const float* rp = res + ((size_t)plane * NV + gidx) * 32;
#pragma unroll
        for (int i = 0; i < 8; ++i) v[i] = ld4(rp + i * 4);
    } else {
#pragma unroll
        for (int i = 0; i < 8; ++i) v[i] = make_float4(0.f, 0.f, 0.f, 0.f);
    }
    float* ob = out + (size_t)plane * 32 * HWC + s;
#pragma unroll
    for (int i = 0; i < 8; ++i) {
        ob[(size_t)(4 * i + 0) * HWC] = v[i].x;
        ob[(size_t)(4 * i + 1) * HWC] = v[i].y;
        ob[(size_t)(4 * i + 2) * HWC] = v[i].z;
        ob[(size_t)(4 * i + 3) * HWC] = v[i].w;
    }
}

// ---------------------------------------------------------------------------
extern "C" void kernel_launch(void* const* d_in, const int* in_sizes, int n_in,
                              void* d_out, int out_size, void* d_ws, size_t ws_size,
                              hipStream_t stream) {
    const float* li_feats = (const float*)d_in[0];
    const int*   li_coors = (const int*)d_in[1];
    const float* ra_feats = (const float*)d_in[2];
    const int*   ra_coors = (const int*)d_in[3];
    const float* w_qkv1 = (const float*)d_in[4];
    const float* b_qkv1 = (const float*)d_in[5];
    const float* w_out1 = (const float*)d_in[6];
    const float* b_out1 = (const float*)d_in[7];
    const float* w_qkv2 = (const float*)d_in[8];
    const float* b_qkv2 = (const float*)d_in[9];
    const float* w_out2 = (const float*)d_in[10];
    const float* b_out2 = (const float*)d_in[11];
    float* out = (float*)d_out;

    char* ws = (char*)d_ws;
    size_t off = 0;
    int*    grids = (int*)(ws + off);    off += (size_t)2 * NB * HWC * 4;    // 8 MB
    uint32* KV    = (uint32*)(ws + off); off += (size_t)2 * KVROWS * 32 * 4; // 51.2 MB (+2 dummy rows)
    float*  res   = (float*)(ws + off);  off += (size_t)NQ * 32 * 4;         // 51.2 MB fp32
    int*    nbr   = (int*)(ws + off);    off += (size_t)NQ * 12 * 4;         // 19.2 MB

    k_fill<<<2048, 256, 0, stream>>>((int4*)grids);

    k_grid<<<(NQ + 255) / 256, 256, 0, stream>>>(li_coors, ra_coors, grids);

    k_proj_kv<<<dim3(3200, 2), 256, 0, stream>>>(
        li_feats, ra_feats, w_qkv1, b_qkv1, w_qkv2, b_qkv2, KV);

    k_nbr<<<(NQ + 255) / 256, 256, 0, stream>>>(li_coors, ra_coors, grids, nbr);

    k_attn<<<NQ / 32, 256, 0, stream>>>(
        nbr, li_feats, ra_feats,
        w_qkv1, b_qkv1, w_out1, b_out1,
        w_qkv2, b_qkv2, w_out2, b_out2,
        KV, res);

    k_densify<<<(2 * NB * HWC) / 256, 256, 0, stream>>>(grids, res, out);
}